// Round 2
// baseline (1737.906 us; speedup 1.0000x reference)
//
#include <hip/hip_runtime.h>

// OctonionConv2d == dense conv: B=16, Cin=64, Cout=128, H=W=128, 3x3, pad 1, fp32.
// Fused weight W[oc][ic][kh][kw] = weight[oc>>3][ic>>3][oc&7][ic&7][kh][kw].
// Block: one (b, h, 16-oc) strip. Thread: 4 oc x 2 w = 8 outputs.
// Weights for the block's 16 oc staged in LDS as [ci][tap][oc16] -> wave-uniform
// ds_read_b128 per tap (broadcast, no bank conflicts).

#define B_    16
#define CIN   64
#define COUT  128
#define H_    128
#define W_    128
#define COB   16          // output channels per block
#define WLDS_N (CIN * 9 * COB)   // 9216 floats = 36 KB

__global__ __launch_bounds__(256, 4)
void oct_conv_kernel(const float* __restrict__ x,
                     const float* __restrict__ wgt,
                     const float* __restrict__ bias,
                     float* __restrict__ out) {
    __shared__ float wlds[WLDS_N];  // [ci][tap][ol]  ol = oc - cb*16

    const int tid = threadIdx.x;
    const int h   = blockIdx.x;           // 0..127
    const int cb  = blockIdx.y;           // 0..7  (16 oc each)
    const int b   = blockIdx.z;           // 0..15

    // ---- stage weights for this block's 16 output channels ----
    // global weight dims (16,8,8,8,3,3): strides out_oct=4608 in_oct=576 p=72 q=9 kh=3 kw=1
    for (int idx = tid; idx < WLDS_N; idx += 256) {
        const int ol  = idx & 15;
        const int rem = idx >> 4;         // ci*9 + tap
        const int tap = rem % 9;
        const int ci  = rem / 9;
        const int oc  = cb * COB + ol;
        wlds[idx] = wgt[(oc >> 3) * 4608 + (ci >> 3) * 576 +
                        (oc & 7) * 72 + (ci & 7) * 9 + tap];
    }
    __syncthreads();

    const int wi  = tid & 63;             // w-pair index
    const int w0  = wi * 2;               // even output column
    const int cs  = tid >> 6;             // 0..3 : which 4-oc group (wave-uniform)
    const int oc0 = cb * COB + cs * 4;

    float acc[4][2];
#pragma unroll
    for (int k = 0; k < 4; ++k) {
        const float bv = bias[oc0 + k];
        acc[k][0] = bv;
        acc[k][1] = bv;
    }

    const float* xb = x + (size_t)b * CIN * H_ * W_;

    for (int ci = 0; ci < CIN; ++ci) {
        const float* xc = xb + ci * H_ * W_;
#pragma unroll
        for (int kh = 0; kh < 3; ++kh) {
            const int hh = h - 1 + kh;
            const bool hok = (unsigned)hh < (unsigned)H_;
            const float* xr = xc + hh * W_;
            // columns w0-1 .. w0+2
            float xv[4];
#pragma unroll
            for (int j = 0; j < 4; ++j) {
                const int col = w0 - 1 + j;
                xv[j] = (hok && (unsigned)col < (unsigned)W_) ? xr[col] : 0.0f;
            }
#pragma unroll
            for (int kw = 0; kw < 3; ++kw) {
                float4 wv = *reinterpret_cast<const float4*>(
                    &wlds[(ci * 9 + kh * 3 + kw) * COB + cs * 4]);
                const float* wa = reinterpret_cast<const float*>(&wv);
#pragma unroll
                for (int k = 0; k < 4; ++k) {
                    acc[k][0] += xv[kw]     * wa[k];  // out col w0   : x col w0-1+kw
                    acc[k][1] += xv[kw + 1] * wa[k];  // out col w0+1 : x col w0+kw
                }
            }
        }
    }

    float* op = out + (((size_t)b * COUT + oc0) * H_ + h) * W_ + w0;
#pragma unroll
    for (int k = 0; k < 4; ++k) {
        float2 st = make_float2(acc[k][0], acc[k][1]);
        *reinterpret_cast<float2*>(op + (size_t)k * H_ * W_) = st;
    }
}

extern "C" void kernel_launch(void* const* d_in, const int* in_sizes, int n_in,
                              void* d_out, int out_size, void* d_ws, size_t ws_size,
                              hipStream_t stream) {
    const float* x    = (const float*)d_in[0];
    const float* wgt  = (const float*)d_in[1];
    const float* bias = (const float*)d_in[2];
    float* out = (float*)d_out;

    dim3 grid(H_, COUT / COB, B_);   // (128, 8, 16)
    oct_conv_kernel<<<grid, 256, 0, stream>>>(x, wgt, bias, out);
}

// Round 3
// 232.162 us; speedup vs baseline: 7.4857x; 7.4857x over previous
//
#include <hip/hip_runtime.h>

// OctonionConv2d == dense conv: B=16, Cin=64, Cout=128, H=W=128, 3x3, pad 1, fp32 in/out.
// bf16 MFMA implicit GEMM: M=(b,h,w), N=oc, K=(tap,ci)=576, mfma_f32_16x16x32_bf16.
// Block = one (b,h) row: 128 w x 128 oc, 4 waves (2m x 2n), wave tile 64x64.
// A: 3 x-rows staged once in LDS as [kh][wp][ci] bf16, XOR-swizzled (G4), no K-loop barriers.
// B: prep kernel lays weights in per-lane fragment order in d_ws; L2-hot global reads, prefetch x2.

#define B_    16
#define CIN   64
#define COUT  128
#define H_    128
#define W_    128
#define HW    (H_*W_)

typedef __attribute__((ext_vector_type(8))) short  short8;
typedef __attribute__((ext_vector_type(4))) float  f32x4;

#define XROW 128               // bytes per wp row: 64 ci * 2B
#define XKH  (132*XROW)        // bytes per kh plane = 16896
#define XLDS_BYTES (3*XKH)     // 50688

static __device__ __forceinline__ unsigned short f2bf(float f) {
    union { float f; unsigned int u; } c; c.f = f;
    unsigned int u = c.u;
    return (unsigned short)((u + 0x7fffu + ((u >> 16) & 1u)) >> 16);  // RNE
}

// w_arr: [s 18][ntile 8][lane 64] x short8.  s: tap=s>>1 (kh=tap/3,kw=tap%3), half=s&1.
// oc = ntile*16 + (lane&15); ci = half*32 + (lane>>4)*8 + j.
__global__ void prep_weights(const float* __restrict__ wgt, unsigned short* __restrict__ warr) {
    int t = blockIdx.x * 256 + threadIdx.x;           // 0..9215
    if (t >= 18*8*64) return;
    int lane = t & 63, ntg = (t >> 6) & 7, s = t >> 9;
    int tap = s >> 1, half = s & 1;
    int kh = tap / 3, kw = tap % 3;
    int oc = ntg*16 + (lane & 15);
    int c0 = half*32 + (lane >> 4)*8;                 // multiple of 8
    // weight fused idx: (oc>>3)*4608 + (ci>>3)*576 + (oc&7)*72 + (ci&7)*9 + kh*3 + kw
    const float* wp = wgt + (oc >> 3)*4608 + (c0 >> 3)*576 + (oc & 7)*72 + kh*3 + kw;
    short8 v;
#pragma unroll
    for (int j = 0; j < 8; ++j) v[j] = (short)f2bf(wp[j*9]);
    *(short8*)(warr + (size_t)t*8) = v;
}

#define ASTEP(S, BCUR, BNXT) do {                                               \
    const int kh_ = ((S) >> 1) / 3, kw_ = ((S) >> 1) % 3, hf_ = (S) & 1;        \
    short8 af[4];                                                               \
    _Pragma("unroll")                                                           \
    for (int mt = 0; mt < 4; ++mt)                                              \
        af[mt] = *(const short8*)(xl + (abase[kw_][hf_] + kh_*XKH + mt*2048));  \
    if ((S) + 2 < 18) {                                                         \
        _Pragma("unroll")                                                       \
        for (int nt = 0; nt < 4; ++nt)                                          \
            BNXT[nt] = wf[(((S)+2)*8 + nt)*64];                                 \
    }                                                                           \
    _Pragma("unroll")                                                           \
    for (int mt = 0; mt < 4; ++mt) {                                            \
        _Pragma("unroll")                                                       \
        for (int nt = 0; nt < 4; ++nt)                                          \
            acc[mt][nt] = __builtin_amdgcn_mfma_f32_16x16x32_bf16(              \
                af[mt], BCUR[nt], acc[mt][nt], 0, 0, 0);                        \
    }                                                                           \
} while (0)

__global__ __launch_bounds__(256, 2)
void conv_mfma(const float* __restrict__ x, const unsigned short* __restrict__ warr,
               const float* __restrict__ bias, float* __restrict__ out) {
    __shared__ __align__(16) unsigned char xl[XLDS_BYTES];   // [kh][wp 0..131][ci] bf16, swizzled

    // XCD-aware bijective swizzle (nwg=2048, %8==0): consecutive-h blocks share an XCD L2.
    int bid = blockIdx.x;
    int swz = (bid & 7)*256 + (bid >> 3);
    int b = swz >> 7, h = swz & 127;

    const int tid = threadIdx.x;

    // ---- stage x rows h-1,h,h+1 -> LDS bf16 transposed [kh][wp][ci], swizzled ----
    // item = (kh, cg, wc): 3*8*128 = 3072 items, 12 iterations. kh uniform per iteration.
#pragma unroll
    for (int it = 0; it < 12; ++it) {
        int idx = it*256 + tid;
        int wc  = idx & 127;
        int cg  = (idx >> 7) & 7;
        int kh  = idx >> 10;
        int hh  = h - 1 + kh;
        bool hok = (unsigned)hh < (unsigned)H_;
        const float* xp = x + (size_t)b*CIN*HW + (size_t)cg*8*HW + hh*W_ + wc;
        short8 pk;
#pragma unroll
        for (int j = 0; j < 8; ++j)
            pk[j] = (short)f2bf(hok ? xp[j*HW] : 0.0f);
        int wp = wc + 1;
        int byte = kh*XKH + wp*XROW + ((cg*16) ^ ((wp & 7) << 4));
        *(short8*)(xl + byte) = pk;
    }
    // zero pad columns wp=0 (x col -1) and wp=129 (x col 128)
    if (tid < 48) {
        int cg = tid & 7, e = (tid >> 3) & 1, kh = tid >> 4;
        int wp = e ? 129 : 0;
        int byte = kh*XKH + wp*XROW + ((cg*16) ^ ((wp & 7) << 4));
        short8 z = {0,0,0,0,0,0,0,0};
        *(short8*)(xl + byte) = z;
    }
    __syncthreads();

    const int lane = tid & 63;
    const int wid  = tid >> 6;
    const int lw = lane & 15, hi = lane >> 4;
    const int wave_m = wid >> 1, wave_n = wid & 1;
    const int wl = wave_m*64 + lw;                    // this lane's m (= w) for A frags

    // A ds_read bases per (kw, half); mt/kh folded into the ds offset immediate.
    int abase[3][2];
#pragma unroll
    for (int kw = 0; kw < 3; ++kw) {
        int wp0 = wl + kw;
        int sw  = (wp0 & 7) << 4;                     // mt*16 doesn't change wp&7
#pragma unroll
        for (int half = 0; half < 2; ++half)
            abase[kw][half] = wp0*XROW + ((half*64 + hi*16) ^ sw);
    }

    // B fragment stream (L2-hot), per-lane pre-arranged: wf[(s*8 + nt)*64]
    const short8* wf = ((const short8*)warr) + (size_t)(wave_n*4)*64 + lane;

    f32x4 acc[4][4] = {};
    short8 bf0[4], bf1[4], bf2[4];
#pragma unroll
    for (int nt = 0; nt < 4; ++nt) {
        bf0[nt] = wf[(0*8 + nt)*64];
        bf1[nt] = wf[(1*8 + nt)*64];
    }

    ASTEP(0,  bf0, bf2); ASTEP(1,  bf1, bf0); ASTEP(2,  bf2, bf1);
    ASTEP(3,  bf0, bf2); ASTEP(4,  bf1, bf0); ASTEP(5,  bf2, bf1);
    ASTEP(6,  bf0, bf2); ASTEP(7,  bf1, bf0); ASTEP(8,  bf2, bf1);
    ASTEP(9,  bf0, bf2); ASTEP(10, bf1, bf0); ASTEP(11, bf2, bf1);
    ASTEP(12, bf0, bf2); ASTEP(13, bf1, bf0); ASTEP(14, bf2, bf1);
    ASTEP(15, bf0, bf2); ASTEP(16, bf1, bf0); ASTEP(17, bf2, bf1);

    // ---- epilogue: bias + store. C/D: col(n)=lane&15, row(m)=(lane>>4)*4+reg ----
    float bv[4];
#pragma unroll
    for (int nt = 0; nt < 4; ++nt) bv[nt] = bias[wave_n*64 + nt*16 + lw];

    const size_t obase = (size_t)b*COUT*HW + (size_t)h*W_;
#pragma unroll
    for (int mt = 0; mt < 4; ++mt) {
#pragma unroll
        for (int nt = 0; nt < 4; ++nt) {
            int oc = wave_n*64 + nt*16 + lw;
            int w0 = wave_m*64 + mt*16 + hi*4;
            f32x4 v = acc[mt][nt];
            v += bv[nt];
            *(f32x4*)(out + obase + (size_t)oc*HW + w0) = v;
        }
    }
}

extern "C" void kernel_launch(void* const* d_in, const int* in_sizes, int n_in,
                              void* d_out, int out_size, void* d_ws, size_t ws_size,
                              hipStream_t stream) {
    const float* x    = (const float*)d_in[0];
    const float* wgt  = (const float*)d_in[1];
    const float* bias = (const float*)d_in[2];
    float* out = (float*)d_out;
    unsigned short* warr = (unsigned short*)d_ws;     // 18*8*64*8*2B = 147456 B

    prep_weights<<<36, 256, 0, stream>>>(wgt, warr);
    conv_mfma<<<2048, 256, 0, stream>>>(x, warr, bias, out);
}

// Round 6
// 216.599 us; speedup vs baseline: 8.0236x; 1.0719x over previous
//
#include <hip/hip_runtime.h>

// OctonionConv2d == dense conv: B=16, Cin=64, Cout=128, H=W=128, 3x3, pad 1, fp32 in/out.
// bf16 MFMA implicit GEMM: M=(b,h,w), N=oc, K=(tap,ci)=576, mfma_f32_16x16x32_bf16.
// R4: block = (b, 2 h-rows): 256 m x 128 oc, 512 thr / 8 waves (4m x 2n), wave tile 64x64.
//     LDS: 4 x-rows [xr][wp][ci] bf16 XOR-swizzled (67.6 KB) -> 2 blocks/CU, stage||MFMA
//     cross-block overlap. B frags depth-1 double-buffered from L2-hot d_ws.

#define B_    16
#define CIN   64
#define COUT  128
#define H_    128
#define W_    128
#define HW    (H_*W_)

typedef __attribute__((ext_vector_type(8))) short  short8;
typedef __attribute__((ext_vector_type(4))) float  f32x4;

#define XROW 128               // bytes per wp row: 64 ci * 2B
#define XKH  (132*XROW)        // bytes per x-row plane = 16896
#define XLDS_BYTES (4*XKH)     // 67584

static __device__ __forceinline__ unsigned short f2bf(float f) {
    union { float f; unsigned int u; } c; c.f = f;
    unsigned int u = c.u;
    return (unsigned short)((u + 0x7fffu + ((u >> 16) & 1u)) >> 16);  // RNE
}

// warr: [s 18][ntile 8][lane 64] x short8.  s: tap=s>>1 (kh=tap/3,kw=tap%3), half=s&1.
// oc = ntile*16 + (lane&15); ci = half*32 + (lane>>4)*8 + j.
__global__ void prep_weights(const float* __restrict__ wgt, unsigned short* __restrict__ warr) {
    int t = blockIdx.x * 256 + threadIdx.x;           // 0..9215
    if (t >= 18*8*64) return;
    int lane = t & 63, ntg = (t >> 6) & 7, s = t >> 9;
    int tap = s >> 1, half = s & 1;
    int kh = tap / 3, kw = tap % 3;
    int oc = ntg*16 + (lane & 15);
    int c0 = half*32 + (lane >> 4)*8;                 // multiple of 8
    // fused weight idx: (oc>>3)*4608 + (ci>>3)*576 + (oc&7)*72 + (ci&7)*9 + kh*3 + kw
    const float* wp = wgt + (oc >> 3)*4608 + (c0 >> 3)*576 + (oc & 7)*72 + kh*3 + kw;
    short8 v;
#pragma unroll
    for (int j = 0; j < 8; ++j) v[j] = (short)f2bf(wp[j*9]);
    *(short8*)(warr + (size_t)t*8) = v;
}

#define ASTEP(S, BCUR, BNXT) do {                                               \
    const int kh_ = ((S) >> 1) / 3, kw_ = ((S) >> 1) % 3, hf_ = (S) & 1;        \
    short8 af[4];                                                               \
    _Pragma("unroll")                                                           \
    for (int mt = 0; mt < 4; ++mt)                                              \
        af[mt] = *(const short8*)(xl + (abase[kw_][hf_] + kh_*XKH + mt*2048));  \
    if ((S) + 1 < 18) {                                                         \
        _Pragma("unroll")                                                       \
        for (int nt = 0; nt < 4; ++nt)                                          \
            BNXT[nt] = wf[(((S)+1)*8 + nt)*64];                                 \
    }                                                                           \
    _Pragma("unroll")                                                           \
    for (int mt = 0; mt < 4; ++mt) {                                            \
        _Pragma("unroll")                                                       \
        for (int nt = 0; nt < 4; ++nt)                                          \
            acc[mt][nt] = __builtin_amdgcn_mfma_f32_16x16x32_bf16(              \
                af[mt], BCUR[nt], acc[mt][nt], 0, 0, 0);                        \
    }                                                                           \
} while (0)

__global__ __launch_bounds__(512, 4)
void conv_mfma(const float* __restrict__ x, const unsigned short* __restrict__ warr,
               const float* __restrict__ bias, float* __restrict__ out) {
    __shared__ __align__(16) unsigned char xl[XLDS_BYTES];  // [xr 0..3][wp 0..129][ci] bf16 swz

    // XCD-aware bijective swizzle (nwg=1024, %8==0)
    int bid = blockIdx.x;
    int swz = (bid & 7)*128 + (bid >> 3);
    int b  = swz >> 6;          // 0..15
    int h0 = (swz & 63)*2;      // 0,2,..,126

    const int tid = threadIdx.x;

    // ---- stage x rows h0-1 .. h0+2 -> LDS bf16 [xr][wp][ci], swizzled ----
    // idx = it*512 + tid: wc = tid&127, cg = (it&1)*4 + (tid>>7), xr = it>>1.
#pragma unroll
    for (int it = 0; it < 8; ++it) {
        const int xr = it >> 1;                     // compile-time per unrolled it
        const int cg = (it & 1)*4 + (tid >> 7);
        const int wc = tid & 127;
        const int hh = h0 - 1 + xr;
        short8 pk;
        if ((unsigned)hh < (unsigned)H_) {          // wave-uniform
            const float* xp = x + (size_t)b*CIN*HW + (size_t)cg*8*HW + hh*W_ + wc;
#pragma unroll
            for (int j = 0; j < 8; ++j) pk[j] = (short)f2bf(xp[j*HW]);
        } else {
            pk = (short8){0,0,0,0,0,0,0,0};
        }
        const int wp = wc + 1;
        const int byte = xr*XKH + wp*XROW + ((cg*16) ^ ((wp & 7) << 4));
        *(short8*)(xl + byte) = pk;
    }
    // zero pad columns wp=0 (x col -1) and wp=129 (x col 128), all 4 planes
    if (tid < 64) {
        const int cg = tid & 7, e = (tid >> 3) & 1, xr = tid >> 4;
        const int wp = e ? 129 : 0;
        const int byte = xr*XKH + wp*XROW + ((cg*16) ^ ((wp & 7) << 4));
        short8 z = {0,0,0,0,0,0,0,0};
        *(short8*)(xl + byte) = z;
    }
    __syncthreads();

    const int lane = tid & 63;
    const int wid  = tid >> 6;                      // 0..7
    const int lw = lane & 15, hi = lane >> 4;
    const int wave_n = wid & 1, wave_m = wid >> 1;  // wave_m 0..3
    const int row_sel = wave_m >> 1;                // output h row within block
    const int wcol = (wave_m & 1)*64;               // w base 0/64
    const int wl = wcol + lw;

    // A ds_read bases per (kw, half); kh and mt folded into the offset immediate.
    int abase[3][2];
#pragma unroll
    for (int kw = 0; kw < 3; ++kw) {
        const int wp0 = wl + kw;
        const int sw  = (wp0 & 7) << 4;             // +mt*16 rows doesn't change wp&7
#pragma unroll
        for (int half = 0; half < 2; ++half)
            abase[kw][half] = row_sel*XKH + wp0*XROW + ((half*64 + hi*16) ^ sw);
    }

    // B fragment stream (L2-hot), per-lane pre-arranged
    const short8* wf = ((const short8*)warr) + (size_t)(wave_n*4)*64 + lane;

    f32x4 acc[4][4] = {};
    short8 ba[4], bb[4];
#pragma unroll
    for (int nt = 0; nt < 4; ++nt) ba[nt] = wf[nt*64];   // s=0

    ASTEP(0,  ba, bb); ASTEP(1,  bb, ba); ASTEP(2,  ba, bb);
    ASTEP(3,  bb, ba); ASTEP(4,  ba, bb); ASTEP(5,  bb, ba);
    ASTEP(6,  ba, bb); ASTEP(7,  bb, ba); ASTEP(8,  ba, bb);
    ASTEP(9,  bb, ba); ASTEP(10, ba, bb); ASTEP(11, bb, ba);
    ASTEP(12, ba, bb); ASTEP(13, bb, ba); ASTEP(14, ba, bb);
    ASTEP(15, bb, ba); ASTEP(16, ba, bb); ASTEP(17, bb, ba);

    // ---- epilogue: bias + store. C/D: col(n)=lane&15, row(m)=(lane>>4)*4+reg ----
    float bv[4];
#pragma unroll
    for (int nt = 0; nt < 4; ++nt) bv[nt] = bias[wave_n*64 + nt*16 + lw];

    const int hh_out = h0 + row_sel;
#pragma unroll
    for (int mt = 0; mt < 4; ++mt) {
#pragma unroll
        for (int nt = 0; nt < 4; ++nt) {
            const int oc = wave_n*64 + nt*16 + lw;
            const int w0 = wcol + mt*16 + hi*4;
            f32x4 v = acc[mt][nt];
            v += bv[nt];
            *(f32x4*)(out + (size_t)b*COUT*HW + (size_t)oc*HW + hh_out*W_ + w0) = v;
        }
    }
}

extern "C" void kernel_launch(void* const* d_in, const int* in_sizes, int n_in,
                              void* d_out, int out_size, void* d_ws, size_t ws_size,
                              hipStream_t stream) {
    const float* x    = (const float*)d_in[0];
    const float* wgt  = (const float*)d_in[1];
    const float* bias = (const float*)d_in[2];
    float* out = (float*)d_out;
    unsigned short* warr = (unsigned short*)d_ws;     // 18*8*64*8*2B = 147456 B

    prep_weights<<<36, 256, 0, stream>>>(wgt, warr);
    conv_mfma<<<1024, 512, 0, stream>>>(x, warr, bias, out);
}